// Round 5
// baseline (8682.021 us; speedup 1.0000x reference)
//
#include <hip/hip_runtime.h>
#include <hip/hip_bf16.h>
#include <hip/hip_cooperative_groups.h>
#include <cstdint>

#define NB 8192
#define TSTEPS 48

namespace cg = cooperative_groups;

typedef __hip_bfloat16 bf16;
typedef short bf16x8 __attribute__((ext_vector_type(8)));
typedef float f32x4 __attribute__((ext_vector_type(4)));

__device__ __forceinline__ float sigf(float x) { return 1.0f / (1.0f + __expf(-x)); }
__device__ __forceinline__ float tanhf_fast(float x) { return 2.0f / (1.0f + __expf(-2.0f * x)) - 1.0f; }

// async global->LDS, 16B/lane. LDS dest = wave-uniform base + lane*16 (m104).
__device__ __forceinline__ void gld_lds16(const void* g, void* l) {
  typedef const __attribute__((address_space(1))) unsigned int* gp_t;
  typedef __attribute__((address_space(3))) unsigned int* lp_t;
  __builtin_amdgcn_global_load_lds(reinterpret_cast<gp_t>(reinterpret_cast<uintptr_t>(g)),
                                   reinterpret_cast<lp_t>(reinterpret_cast<uintptr_t>(l)),
                                   16, 0, 0);
}

// gate-interleaved packed gate-column order: p = (u>>4)*64 + g*16 + (u&15)
__device__ __forceinline__ int orig_row_p(int p) {
  int ug = p >> 6, g = (p >> 4) & 3, s = p & 15;
  return g * 256 + ug * 16 + s;  // original row j = g*256 + u
}
// K-swizzle: original chunk c of row r stored at position c ^ ((r>>1)&3).
__device__ __forceinline__ int unswz_col(int colp, int r) {
  int cc = ((colp >> 3) & 3) ^ ((r >> 1) & 3);
  return (colp & ~31) | (cc << 3) | (colp & 7);
}

// ---------------- feats precompute: [T, N, 32] bf16 (swizzled chunks, cols 16..31 zero) ----
__global__ void feats_kernel(const float* __restrict__ x, const float* __restrict__ coords,
                             const float* __restrict__ env, const float* __restrict__ areas,
                             const float* __restrict__ bird, bf16* __restrict__ feats) {
  int idx = blockIdx.x * 256 + threadIdx.x;  // = t*NB + n
  int n = idx & (NB - 1);
  int t = idx >> 13;
  __align__(16) bf16 v[32];
  v[0] = __float2bfloat16(x[n * TSTEPS + t]);
  v[1] = __float2bfloat16(coords[n * 2 + 0]);
  v[2] = __float2bfloat16(coords[n * 2 + 1]);
#pragma unroll
  for (int e = 0; e < 10; ++e) v[3 + e] = __float2bfloat16(env[(n * 10 + e) * TSTEPS + t]);
  v[13] = __float2bfloat16(areas[n]);
  v[14] = __float2bfloat16(bird[(n * 2 + 0) * TSTEPS + t]);
  v[15] = __float2bfloat16(bird[(n * 2 + 1) * TSTEPS + t]);
#pragma unroll
  for (int f = 16; f < 32; ++f) v[f] = __float2bfloat16(0.0f);
  bf16* dst = feats + (size_t)idx * 32;
  int sw = (n >> 1) & 3;
#pragma unroll
  for (int c = 0; c < 4; ++c) ((bf16x8*)dst)[c ^ sw] = ((const bf16x8*)v)[c];
}

// ---------------- weight packing (gate-interleaved rows + K-chunk swizzle) ----------------
__global__ void packA_kernel(const float* __restrict__ W_hh0, const float* __restrict__ W_ih0,
                             const float* __restrict__ W_in, bf16* __restrict__ WA) {
  int idx = blockIdx.x * 256 + threadIdx.x;  // < 1024*288
  int p = idx / 288, colp = idx % 288;
  int j = orig_row_p(p);
  int k = unswz_col(colp, p);
  float val = 0.0f;
  if (k < 256) {
    val = W_hh0[j * 256 + k];
  } else if (k < 272) {
    int f = k - 256;
    float s = 0.0f;
    for (int kk = 0; kk < 256; ++kk) s += W_ih0[j * 256 + kk] * W_in[kk * 16 + f];
    val = s;
  }
  WA[(size_t)p * 288 + colp] = __float2bfloat16(val);
}

__global__ void packB_kernel(const float* __restrict__ W_ih1, const float* __restrict__ W_hh1,
                             bf16* __restrict__ WB) {
  int idx = blockIdx.x * 256 + threadIdx.x;  // < 1024*512
  int p = idx >> 9, colp = idx & 511;
  int j = orig_row_p(p);
  int k = unswz_col(colp, p);
  float val = (k < 256) ? W_ih1[j * 256 + k] : W_hh1[j * 256 + (k - 256)];
  WB[(size_t)p * 512 + colp] = __float2bfloat16(val);
}

__global__ void packBias_kernel(const float* __restrict__ b_ih, const float* __restrict__ b_hh,
                                float* __restrict__ bA, float* __restrict__ bB) {
  int idx = blockIdx.x * 256 + threadIdx.x;  // < 2048
  int layer = idx >> 10, r = idx & 1023;
  float v = b_ih[layer * 1024 + r] + b_hh[layer * 1024 + r];
  if (layer == 0) bA[r] = v; else bB[r] = v;
}

// ---------------- R5: persistent cooperative kernel ----------------
// One dispatch; 49 steps with grid.sync between. Block keeps (rowbase, q, role) forever:
// role A = layer0 at t=i (i<=47), role B = layer1 at t=i-1 (i>=1) — same per-step work as
// the R2 combined launch, minus: 49x launch/ramp/prologue, c memory round-trips (c lives
// in 16 VGPRs/thread, block owns its c-slice exclusively), cold-L2 re-fetch per launch.
// K-loop = R2's proven 2-phase dbuf structure, unchanged.
// Mapping keeps each rowgroup's 16 blocks on one XCD (perf-only; grid.sync fences handle
// correctness regardless of mapping).
__global__ __launch_bounds__(256, 4) void lstm_persist(
    bf16* __restrict__ H00, bf16* __restrict__ H10,
    bf16* __restrict__ H01, bf16* __restrict__ H11,
    const bf16* __restrict__ feats,
    const bf16* __restrict__ WA, const bf16* __restrict__ WB,
    const float* __restrict__ bA, const float* __restrict__ bB,
    float* __restrict__ out) {
  cg::grid_group grid = cg::this_grid();
  __shared__ __align__(16) bf16 As[2 * 128 * 32];
  __shared__ __align__(16) bf16 Bs[2 * 128 * 32];

  const int tid = threadIdx.x;
  const int wid = tid >> 6, lane = tid & 63;
  const int quad = lane >> 4, l16 = lane & 15;
  const int mb = (wid >> 1) * 64, nb = (wid & 1) * 64;

  // bid -> (xcd, rowgroup, role, q): all 16 blocks of a rowgroup share an XCD (bid&7)
  const int bid = blockIdx.x;
  const int xcd = bid & 7, slot = bid >> 3;       // slot 0..127 within XCD
  const int isA = (slot & 15) >> 3, q = slot & 7; // 8 B-blocks + 8 A-blocks per rowgroup
  const int rowbase = (xcd * 8 + (slot >> 4)) * 128;

  const bf16* Wp = isA ? WA : WB;
  const int KW = isA ? 288 : 512;
  const int KITERS = isA ? 9 : 16;

  const int r4 = lane >> 2;                      // 0..15
  const int ch = (lane & 3) * 8;                 // staging chunk (linear)
  const int cb = (quad ^ ((l16 >> 1) & 3)) * 8;  // swizzled read chunk (conflict-free)
  const int arow = wid * 32 + r4;
  const bf16* WGrow = Wp + (size_t)(q * 128 + arow) * KW + ch;

  const int u = (q * 2 + (nb >> 6)) * 16 + l16;
  const float* bias = isA ? bA : bB;
  const float bi = bias[u], bf_ = bias[256 + u], bg = bias[512 + u], bo = bias[768 + u];
  float* out_h = out + (size_t)(isA ? 0 : 1) * NB * 256;
  float* out_c = out + (size_t)(isA ? 2 : 3) * NB * 256;

  float creg[16];  // persistent cell state: this block's exclusive c-slice
#pragma unroll
  for (int k2 = 0; k2 < 16; ++k2) creg[k2] = 0.f;

  for (int i = 0; i <= 48; ++i) {
    if (isA ? (i <= 47) : (i >= 1)) {
      // parities: h0(i-1)=H0[(i+1)&1], h1(i-2)=H1[i&1]; A writes h0(i)=H0[i&1],
      // B writes h1(i-1)=H1[(i+1)&1]
      const bf16* h0r = (i & 1) ? H00 : H01;
      const bf16* h1r = (i & 1) ? H11 : H10;
      bf16* hw = isA ? ((i & 1) ? H01 : H00) : ((i & 1) ? H10 : H11);

      f32x4 acc[4][4];
#pragma unroll
      for (int a = 0; a < 4; ++a)
#pragma unroll
        for (int b = 0; b < 4; ++b) acc[a][b] = f32x4{0.f, 0.f, 0.f, 0.f};

      auto stage = [&](int kb, int buf) {
        const bf16* asrc;
        int astr;
        if (isA && kb == 8) {
          asrc = feats + (size_t)i * (NB * 32);
          astr = 32;
        } else if (!isA && kb >= 8) {
          asrc = h1r + (kb - 8) * 32;
          astr = 256;
        } else {
          asrc = h0r + kb * 32;
          astr = 256;
        }
        const bf16* ga = asrc + (size_t)(rowbase + arow) * astr + ch;
        bf16* lA = As + buf * (128 * 32) + wid * (32 * 32);
        gld_lds16(ga, lA);
        gld_lds16(ga + (size_t)16 * astr, lA + 16 * 32);
        const bf16* gb = WGrow + kb * 32;
        bf16* lB = Bs + buf * (128 * 32) + wid * (32 * 32);
        gld_lds16(gb, lB);
        gld_lds16(gb + (size_t)16 * KW, lB + 16 * 32);
      };

      stage(0, 0);
      __syncthreads();  // vmcnt drain publishes buf 0
      for (int kb = 0; kb < KITERS; ++kb) {
        const int buf = kb & 1;
        if (kb + 1 < KITERS) stage(kb + 1, buf ^ 1);
        const bf16* Ab = As + buf * (128 * 32);
        const bf16* Bb = Bs + buf * (128 * 32);
        bf16x8 af[4], bfr[4];
#pragma unroll
        for (int a = 0; a < 4; ++a) af[a] = *(const bf16x8*)(Ab + (mb + a * 16 + l16) * 32 + cb);
#pragma unroll
        for (int b = 0; b < 4; ++b) bfr[b] = *(const bf16x8*)(Bb + (nb + b * 16 + l16) * 32 + cb);
#pragma unroll
        for (int a = 0; a < 4; ++a)
#pragma unroll
          for (int b = 0; b < 4; ++b)
            acc[a][b] = __builtin_amdgcn_mfma_f32_16x16x32_bf16(af[a], bfr[b], acc[a][b], 0, 0, 0);
        if (kb + 1 < KITERS) __syncthreads();
      }

      // register-local epilogue; c stays in creg
      const int last = isA ? (i == 47) : (i == 48);
#pragma unroll
      for (int a = 0; a < 4; ++a) {
#pragma unroll
        for (int rr = 0; rr < 4; ++rr) {
          const int n = rowbase + mb + a * 16 + quad * 4 + rr;
          const size_t ci = (size_t)n * 256 + u;
          float gi = sigf(acc[a][0][rr] + bi);
          float gf = sigf(acc[a][1][rr] + bf_);
          float gg = tanhf_fast(acc[a][2][rr] + bg);
          float go = sigf(acc[a][3][rr] + bo);
          float cn = gf * creg[a * 4 + rr] + gi * gg;
          float hn = go * tanhf_fast(cn);
          creg[a * 4 + rr] = cn;
          const int col = (u & ~31) | ((((u >> 3) & 3) ^ ((n >> 1) & 3)) << 3) | (u & 7);
          hw[(size_t)n * 256 + col] = __float2bfloat16(hn);
          if (last) { out_h[ci] = hn; out_c[ci] = cn; }
        }
      }
    }
    if (i < 48) grid.sync();
  }
}

// ---------------- fallback: R2 per-step kernel (verified best, 1376 us) ----------------
__global__ __launch_bounds__(256, 4) void lstm_step(
    const bf16* __restrict__ h0r, bf16* __restrict__ h0w,
    const bf16* __restrict__ h1r, bf16* __restrict__ h1w,
    const bf16* __restrict__ feats,
    const bf16* __restrict__ WA, const bf16* __restrict__ WB,
    const float* __restrict__ bA, const float* __restrict__ bB,
    bf16* __restrict__ c0, bf16* __restrict__ c1,
    float* __restrict__ out, int tA, int tB, int phase0, int lastA, int lastB) {
  __shared__ __align__(16) bf16 As[2 * 128 * 32];
  __shared__ __align__(16) bf16 Bs[2 * 128 * 32];

  const int tid = threadIdx.x;
  const int wid = tid >> 6, lane = tid & 63;
  const int quad = lane >> 4, l16 = lane & 15;
  const int mb = (wid >> 1) * 64, nb = (wid & 1) * 64;
  const int rowbase = blockIdx.x * 128;
  const int q = blockIdx.y;
  const int isA = blockIdx.z + phase0;

  const bf16* Wp = isA ? WA : WB;
  const int KW = isA ? 288 : 512;
  const int KITERS = isA ? 9 : 16;

  f32x4 acc[4][4];
#pragma unroll
  for (int i = 0; i < 4; ++i)
#pragma unroll
    for (int j = 0; j < 4; ++j) acc[i][j] = f32x4{0.f, 0.f, 0.f, 0.f};

  const int r4 = lane >> 2;
  const int ch = (lane & 3) * 8;
  const int cb = (quad ^ ((l16 >> 1) & 3)) * 8;
  const int arow = wid * 32 + r4;
  const bf16* WGrow = Wp + (size_t)(q * 128 + arow) * KW + ch;

  auto stage = [&](int kb, int buf) {
    const bf16* asrc;
    int astr;
    if (isA && kb == 8) {
      asrc = feats + (size_t)tA * (NB * 32);
      astr = 32;
    } else if (!isA && kb >= 8) {
      asrc = h1r + (kb - 8) * 32;
      astr = 256;
    } else {
      asrc = h0r + kb * 32;
      astr = 256;
    }
    const bf16* ga = asrc + (size_t)(rowbase + arow) * astr + ch;
    bf16* lA = As + buf * (128 * 32) + wid * (32 * 32);
    gld_lds16(ga, lA);
    gld_lds16(ga + (size_t)16 * astr, lA + 16 * 32);
    const bf16* gb = WGrow + kb * 32;
    bf16* lB = Bs + buf * (128 * 32) + wid * (32 * 32);
    gld_lds16(gb, lB);
    gld_lds16(gb + (size_t)16 * KW, lB + 16 * 32);
  };

  stage(0, 0);
  __syncthreads();

  for (int kb = 0; kb < KITERS; ++kb) {
    const int buf = kb & 1;
    if (kb + 1 < KITERS) stage(kb + 1, buf ^ 1);
    const bf16* Ab = As + buf * (128 * 32);
    const bf16* Bb = Bs + buf * (128 * 32);
    bf16x8 af[4], bfr[4];
#pragma unroll
    for (int i = 0; i < 4; ++i) af[i] = *(const bf16x8*)(Ab + (mb + i * 16 + l16) * 32 + cb);
#pragma unroll
    for (int j = 0; j < 4; ++j) bfr[j] = *(const bf16x8*)(Bs + buf * (128 * 32) + (nb + j * 16 + l16) * 32 + cb);
#pragma unroll
    for (int i = 0; i < 4; ++i)
#pragma unroll
      for (int j = 0; j < 4; ++j)
        acc[i][j] = __builtin_amdgcn_mfma_f32_16x16x32_bf16(af[i], bfr[j], acc[i][j], 0, 0, 0);
    if (kb + 1 < KITERS) __syncthreads();
    (void)Bb;
  }

  const int u = (q * 2 + (nb >> 6)) * 16 + l16;
  const float* bias = isA ? bA : bB;
  bf16* cst = isA ? c0 : c1;
  bf16* hout = isA ? h0w : h1w;
  const int last = isA ? lastA : lastB;
  float* out_h = out + (size_t)(isA ? 0 : 1) * NB * 256;
  float* out_c = out + (size_t)(isA ? 2 : 3) * NB * 256;
  const float bi = bias[u], bf_ = bias[256 + u], bg = bias[512 + u], bo = bias[768 + u];
#pragma unroll
  for (int i = 0; i < 4; ++i) {
#pragma unroll
    for (int rr = 0; rr < 4; ++rr) {
      const int n = rowbase + mb + i * 16 + quad * 4 + rr;
      const size_t ci = (size_t)n * 256 + u;
      float gi = sigf(acc[i][0][rr] + bi);
      float gf = sigf(acc[i][1][rr] + bf_);
      float gg = tanhf_fast(acc[i][2][rr] + bg);
      float go = sigf(acc[i][3][rr] + bo);
      float c = __bfloat162float(cst[ci]);
      float cn = gf * c + gi * gg;
      float hn = go * tanhf_fast(cn);
      if (!last) cst[ci] = __float2bfloat16(cn);
      const int col = (u & ~31) | ((((u >> 3) & 3) ^ ((n >> 1) & 3)) << 3) | (u & 7);
      hout[(size_t)n * 256 + col] = __float2bfloat16(hn);
      if (last) { out_h[ci] = hn; out_c[ci] = cn; }
    }
  }
}

extern "C" void kernel_launch(void* const* d_in, const int* in_sizes, int n_in,
                              void* d_out, int out_size, void* d_ws, size_t ws_size,
                              hipStream_t stream) {
  const float* x = (const float*)d_in[0];
  const float* coords = (const float*)d_in[1];
  const float* env = (const float*)d_in[2];
  const float* areas = (const float*)d_in[3];
  const float* bird = (const float*)d_in[4];
  const float* W_in = (const float*)d_in[5];
  const float* W_ih = (const float*)d_in[6];  // [2,1024,256]
  const float* W_hh = (const float*)d_in[7];  // [2,1024,256]
  const float* b_ih = (const float*)d_in[8];  // [2,1024]
  const float* b_hh = (const float*)d_in[9];  // [2,1024]
  float* out = (float*)d_out;

  const size_t MB = 1 << 20;
  char* w0 = (char*)d_ws;
  auto H0 = [&](int i) { return (bf16*)(w0 + (size_t)i * 8 * MB); };
  auto H1 = [&](int i) { return (bf16*)(w0 + 4 * MB + (size_t)i * 8 * MB); };
  bf16* c0 = (bf16*)(w0 + 16 * MB);
  bf16* c1 = (bf16*)(w0 + 20 * MB);
  bf16* feats = (bf16*)(w0 + 24 * MB);
  bf16* WA = (bf16*)(w0 + 48 * MB);
  bf16* WB = (bf16*)(w0 + 49 * MB);
  float* bA = (float*)(w0 + 50 * MB);
  float* bB = (float*)(w0 + 50 * MB + 4096);

  // zero H0(1), H1(1) (initial state) and c0, c1 (fallback path) — [8MB, 24MB)
  hipMemsetAsync(w0 + 8 * MB, 0, 16 * MB, stream);

  feats_kernel<<<(NB * TSTEPS) / 256, 256, 0, stream>>>(x, coords, env, areas, bird, feats);
  packA_kernel<<<(1024 * 288) / 256, 256, 0, stream>>>(W_hh, W_ih, W_in, WA);
  packB_kernel<<<(1024 * 512) / 256, 256, 0, stream>>>(W_ih + 1024 * 256, W_hh + 1024 * 256, WB);
  packBias_kernel<<<2048 / 256, 256, 0, stream>>>(b_ih, b_hh, bA, bB);

  // persistent cooperative path
  bf16 *h00 = H0(0), *h10 = H1(0), *h01 = H0(1), *h11 = H1(1);
  const bf16 *featsp = feats, *WAp = WA, *WBp = WB;
  const float *bAp = bA, *bBp = bB;
  float* outp = out;
  void* kargs[] = {&h00, &h10, &h01, &h11, &featsp, &WAp, &WBp, &bAp, &bBp, &outp};
  hipError_t ce = hipLaunchCooperativeKernel((void*)lstm_persist, dim3(1024), dim3(256),
                                             kargs, 0, stream);
  if (ce != hipSuccess) {
    // fallback: R2 launch sequence (verified 1376 us)
    lstm_step<<<dim3(64, 8, 1), 256, 0, stream>>>(
        H0(1), H0(0), H1(0), H1(1), feats, WA, WB, bA, bB, c0, c1, out,
        0, 0, 1, 0, 0);
    for (int s2 = 0; s2 <= 46; ++s2) {
      int pa = (s2 + 1) & 1, pb = s2 & 1;
      lstm_step<<<dim3(64, 8, 2), 256, 0, stream>>>(
          H0(pb), H0(pa), H1(pa), H1(pb), feats, WA, WB, bA, bB, c0, c1, out,
          s2 + 1, s2, 0, (s2 == 46), 0);
    }
    lstm_step<<<dim3(64, 8, 1), 256, 0, stream>>>(
        H0(1), H0(0), H1(0), H1(1), feats, WA, WB, bA, bB, c0, c1, out,
        0, 47, 0, 0, 1);
  }
}

// Round 6
// 4395.561 us; speedup vs baseline: 1.9752x; 1.9752x over previous
//
#include <hip/hip_runtime.h>
#include <hip/hip_bf16.h>
#include <cstdint>

#define NB 8192
#define TSTEPS 48

typedef __hip_bfloat16 bf16;
typedef short bf16x8 __attribute__((ext_vector_type(8)));
typedef float f32x4 __attribute__((ext_vector_type(4)));

__device__ __forceinline__ float sigf(float x) { return 1.0f / (1.0f + __expf(-x)); }
__device__ __forceinline__ float tanhf_fast(float x) { return 2.0f / (1.0f + __expf(-2.0f * x)) - 1.0f; }

// async global->LDS, 16B/lane. LDS dest = wave-uniform base + lane*16 (m104).
__device__ __forceinline__ void gld_lds16(const void* g, void* l) {
  typedef const __attribute__((address_space(1))) unsigned int* gp_t;
  typedef __attribute__((address_space(3))) unsigned int* lp_t;
  __builtin_amdgcn_global_load_lds(reinterpret_cast<gp_t>(reinterpret_cast<uintptr_t>(g)),
                                   reinterpret_cast<lp_t>(reinterpret_cast<uintptr_t>(l)),
                                   16, 0, 0);
}

// gate-interleaved packed gate-column order: p = (u>>4)*64 + g*16 + (u&15)
// -> N-tile j of wave w is gate (j&3) of unit group 2w+(j>>2); thread's 4 gate frags
//    for unit u = (2w + j>>2)*16 + l16 line up for a register-local cell.
__device__ __forceinline__ int orig_row_p(int p) {
  int ug = p >> 6, g = (p >> 4) & 3, s = p & 15;
  return g * 256 + ug * 16 + s;  // original row j = g*256 + u
}

// ---------------- feats precompute: [T, N, 32] bf16 (linear chunks; cols 16..31 zero) ----
__global__ void feats_kernel(const float* __restrict__ x, const float* __restrict__ coords,
                             const float* __restrict__ env, const float* __restrict__ areas,
                             const float* __restrict__ bird, bf16* __restrict__ feats) {
  int idx = blockIdx.x * 256 + threadIdx.x;  // = t*NB + n
  int n = idx & (NB - 1);
  int t = idx >> 13;
  __align__(16) bf16 v[32];
  v[0] = __float2bfloat16(x[n * TSTEPS + t]);
  v[1] = __float2bfloat16(coords[n * 2 + 0]);
  v[2] = __float2bfloat16(coords[n * 2 + 1]);
#pragma unroll
  for (int e = 0; e < 10; ++e) v[3 + e] = __float2bfloat16(env[(n * 10 + e) * TSTEPS + t]);
  v[13] = __float2bfloat16(areas[n]);
  v[14] = __float2bfloat16(bird[(n * 2 + 0) * TSTEPS + t]);
  v[15] = __float2bfloat16(bird[(n * 2 + 1) * TSTEPS + t]);
#pragma unroll
  for (int f = 16; f < 32; ++f) v[f] = __float2bfloat16(0.0f);
  bf16* dst = feats + (size_t)idx * 32;
#pragma unroll
  for (int c = 0; c < 4; ++c) ((bf16x8*)dst)[c] = ((const bf16x8*)v)[c];
}

// ---------------- weight packing: per-wave frag-linear order for direct L2->VGPR loads ----
// PWA[w][kb][j][lane][e] (w<8, kb<9, j<8, lane<64, e<8): element = WA[p][k] with
// p = w*128 + j*16 + (lane&15) (gate-interleaved row), k = kb*32 + (lane>>4)*8 + e.
// Per (w,kb,j) = 1KB contiguous -> each wave's 8 frag loads/iter are perfectly coalesced.
__global__ void packPWA(const float* __restrict__ W_hh0, const float* __restrict__ W_ih0,
                        const float* __restrict__ W_in, bf16* __restrict__ PWA) {
  int idx = blockIdx.x * 256 + threadIdx.x;  // < 8*9*8*64*8 = 294912
  int w = idx / 36864, r = idx - w * 36864;
  int kb = r >> 12, j = (r >> 9) & 7, lane = (r >> 3) & 63, e = r & 7;
  int l16 = lane & 15, quad = lane >> 4;
  int p = w * 128 + j * 16 + l16;
  int jrow = orig_row_p(p);
  int k = kb * 32 + quad * 8 + e;
  float val = 0.0f;
  if (k < 256) {
    val = W_hh0[jrow * 256 + k];
  } else if (k < 272) {
    int f = k - 256;
    float s = 0.0f;
    for (int kk = 0; kk < 256; ++kk) s += W_ih0[jrow * 256 + kk] * W_in[kk * 16 + f];
    val = s;  // Wc0 = W_ih0 @ W_in fused input projection
  }
  PWA[idx] = __float2bfloat16(val);
}

// PWB[w][kb][j][lane][e] (kb<16): k<256 -> W_ih1 (h0 operand), else W_hh1 (h1 operand).
__global__ void packPWB(const float* __restrict__ W_ih1, const float* __restrict__ W_hh1,
                        bf16* __restrict__ PWB) {
  int idx = blockIdx.x * 256 + threadIdx.x;  // < 8*16*8*64*8 = 524288
  int w = idx >> 16, r = idx & 65535;
  int kb = r >> 12, j = (r >> 9) & 7, lane = (r >> 3) & 63, e = r & 7;
  int l16 = lane & 15, quad = lane >> 4;
  int p = w * 128 + j * 16 + l16;
  int jrow = orig_row_p(p);
  int k = kb * 32 + quad * 8 + e;
  float val = (k < 256) ? W_ih1[jrow * 256 + k] : W_hh1[jrow * 256 + (k - 256)];
  PWB[idx] = __float2bfloat16(val);
}

// bias packed [gate][unit] (== original j = g*256+u); sum ih+hh
__global__ void packBias_kernel(const float* __restrict__ b_ih, const float* __restrict__ b_hh,
                                float* __restrict__ bA, float* __restrict__ bB) {
  int idx = blockIdx.x * 256 + threadIdx.x;  // < 2048
  int layer = idx >> 10, r = idx & 1023;
  float v = b_ih[layer * 1024 + r] + b_hh[layer * 1024 + r];
  if (layer == 0) bA[r] = v; else bB[r] = v;
}

// ---------------- R6: single persistent kernel, ZERO inter-block communication ----------
// The recurrence is row-local in n: block owns 32 rows x ALL 1024 gate cols and runs all
// 48 steps x 2 layers locally. h0/h1 tiles live in LDS (never global); c in VGPRs.
// Weights stream L2->VGPR frags each step (1.6 MB/CU/step, coalesced via PW* packing) —
// the only recurring traffic; L2-resident per XCD. No launches, no grid.sync (R5: 150us/
// step), no vmcnt(0)-on-global-critical-path.
// 256 blocks x 512 thr (8 waves, wave = M32 x N128 = 2 Mtiles x 8 Ntiles).
// LDS h rows padded to 264 elems -> frag ds_read_b128 is 2-way bank (free, m136).
__global__ __launch_bounds__(512, 2) void lstm_all(
    const bf16* __restrict__ feats, const bf16* __restrict__ PWA,
    const bf16* __restrict__ PWB, const float* __restrict__ bA,
    const float* __restrict__ bB, float* __restrict__ out) {
  __shared__ __align__(16) bf16 h0s[32 * 264];
  __shared__ __align__(16) bf16 h1s[32 * 264];
  __shared__ __align__(16) bf16 fts[32 * 32];

  const int tid = threadIdx.x;
  const int wid = tid >> 6, lane = tid & 63;
  const int quad = lane >> 4, l16 = lane & 15;
  const int rowbase = blockIdx.x * 32;

  // zero initial h state (c zeroed in regs)
  for (int i = tid; i < 32 * 264; i += 512) {
    h0s[i] = __float2bfloat16(0.0f);
    h1s[i] = __float2bfloat16(0.0f);
  }
  // stage feats t=0 (2KB, wave 0)
  if (wid == 0) {
    const bf16* f = feats + (size_t)rowbase * 32 + lane * 8;
    gld_lds16(f, fts);
    gld_lds16(f + 512, fts + 512);
  }
  __syncthreads();  // emits vmcnt(0) drain -> fts + zeros published

  // per-lane bias regs: bs[ug*4+g] for unit u = (2*wid+ug)*16+l16
  float bsA[8], bsB[8];
#pragma unroll
  for (int ug = 0; ug < 2; ++ug)
#pragma unroll
    for (int g = 0; g < 4; ++g) {
      int u = (2 * wid + ug) * 16 + l16;
      bsA[ug * 4 + g] = bA[g * 256 + u];
      bsB[ug * 4 + g] = bB[g * 256 + u];
    }

  float c0r[16], c1r[16];
#pragma unroll
  for (int i = 0; i < 16; ++i) { c0r[i] = 0.f; c1r[i] = 0.f; }

  const int loff = lane * 8;  // 16B/lane within a 1KB frag group
  const bf16* wA = PWA + (size_t)wid * 36864 + loff;
  const bf16* wB = PWB + (size_t)wid * 65536 + loff;
  float* out_h0 = out;
  float* out_h1 = out + (size_t)NB * 256;
  float* out_c0 = out + (size_t)2 * NB * 256;
  float* out_c1 = out + (size_t)3 * NB * 256;

  f32x4 acc[2][8];
  bf16x8 bw[2][8];

  // register-local cell: thread's 8 N-frags = 4 gates x 2 unit-groups of unit u
  auto cell = [&](float* cr, bf16* hs, const float* bs, float* oh, float* oc, int last) {
#pragma unroll
    for (int m = 0; m < 2; ++m)
#pragma unroll
      for (int ug = 0; ug < 2; ++ug)
#pragma unroll
        for (int rr = 0; rr < 4; ++rr) {
          const int n = m * 16 + quad * 4 + rr;
          const int u = (2 * wid + ug) * 16 + l16;
          float gi = sigf(acc[m][ug * 4 + 0][rr] + bs[ug * 4 + 0]);
          float gf = sigf(acc[m][ug * 4 + 1][rr] + bs[ug * 4 + 1]);
          float gg = tanhf_fast(acc[m][ug * 4 + 2][rr] + bs[ug * 4 + 2]);
          float go = sigf(acc[m][ug * 4 + 3][rr] + bs[ug * 4 + 3]);
          const int ci = m * 8 + ug * 4 + rr;
          float cn = gf * cr[ci] + gi * gg;
          float hn = go * tanhf_fast(cn);
          cr[ci] = cn;
          hs[n * 264 + u] = __float2bfloat16(hn);
          if (last) {
            size_t gi2 = (size_t)(rowbase + n) * 256 + u;
            oh[gi2] = hn;
            oc[gi2] = cn;
          }
        }
  };

  for (int t = 0; t < TSTEPS; ++t) {
    const int last = (t == TSTEPS - 1);
    // ---- layer 0: gates = [h0 | feats_t] @ WA^T (K = 9x32) ----
#pragma unroll
    for (int m = 0; m < 2; ++m)
#pragma unroll
      for (int j = 0; j < 8; ++j) acc[m][j] = f32x4{0.f, 0.f, 0.f, 0.f};
#pragma unroll
    for (int j = 0; j < 8; ++j) bw[0][j] = *(const bf16x8*)(wA + j * 512);
#pragma unroll
    for (int kb = 0; kb < 9; ++kb) {
      if (kb < 8) {
#pragma unroll
        for (int j = 0; j < 8; ++j)
          bw[(kb + 1) & 1][j] = *(const bf16x8*)(wA + (kb + 1) * 4096 + j * 512);
      } else {
#pragma unroll
        for (int j = 0; j < 8; ++j)  // cross-GEMM prefetch: layer-1 kb=0 frags
          bw[1][j] = *(const bf16x8*)(wB + j * 512);
      }
      bf16x8 af[2];
      if (kb < 8) {
#pragma unroll
        for (int m = 0; m < 2; ++m)
          af[m] = *(const bf16x8*)(h0s + (m * 16 + l16) * 264 + kb * 32 + quad * 8);
      } else {
#pragma unroll
        for (int m = 0; m < 2; ++m)
          af[m] = *(const bf16x8*)(fts + (m * 16 + l16) * 32 + quad * 8);
      }
#pragma unroll
      for (int m = 0; m < 2; ++m)
#pragma unroll
        for (int j = 0; j < 8; ++j)
          acc[m][j] = __builtin_amdgcn_mfma_f32_16x16x32_bf16(af[m], bw[kb & 1][j], acc[m][j], 0, 0, 0);
    }
    __syncthreads();  // all waves done reading h0(t-1)/fts (drains bw[1] prefetch too)
    cell(c0r, h0s, bsA, out_h0, out_c0, last);
    __syncthreads();  // h0(t) published

    // ---- layer 1: gates = [h0(t) | h1(t-1)] @ WB^T (K = 16x32); bw[1] holds kb=0 ----
#pragma unroll
    for (int m = 0; m < 2; ++m)
#pragma unroll
      for (int j = 0; j < 8; ++j) acc[m][j] = f32x4{0.f, 0.f, 0.f, 0.f};
#pragma unroll
    for (int kb = 0; kb < 16; ++kb) {
      if (kb < 15) {
#pragma unroll
        for (int j = 0; j < 8; ++j)
          bw[kb & 1][j] = *(const bf16x8*)(wB + (kb + 1) * 4096 + j * 512);
      }
      bf16x8 af[2];
      if (kb < 8) {
#pragma unroll
        for (int m = 0; m < 2; ++m)
          af[m] = *(const bf16x8*)(h0s + (m * 16 + l16) * 264 + kb * 32 + quad * 8);
      } else {
#pragma unroll
        for (int m = 0; m < 2; ++m)
          af[m] = *(const bf16x8*)(h1s + (m * 16 + l16) * 264 + (kb - 8) * 32 + quad * 8);
      }
#pragma unroll
      for (int m = 0; m < 2; ++m)
#pragma unroll
        for (int j = 0; j < 8; ++j)
          acc[m][j] = __builtin_amdgcn_mfma_f32_16x16x32_bf16(af[m], bw[(kb + 1) & 1][j], acc[m][j], 0, 0, 0);
    }
    // stage feats t+1 (drained by the next barrier's vmcnt(0); read next step)
    if (t < TSTEPS - 1 && wid == 0) {
      const bf16* f = feats + ((size_t)(t + 1) * NB + rowbase) * 32 + lane * 8;
      gld_lds16(f, fts);
      gld_lds16(f + 512, fts + 512);
    }
    __syncthreads();  // h1(t-1) reads done; fts(t+1) published
    cell(c1r, h1s, bsB, out_h1, out_c1, last);
    __syncthreads();  // h1(t) published for next step
  }
}

extern "C" void kernel_launch(void* const* d_in, const int* in_sizes, int n_in,
                              void* d_out, int out_size, void* d_ws, size_t ws_size,
                              hipStream_t stream) {
  const float* x = (const float*)d_in[0];
  const float* coords = (const float*)d_in[1];
  const float* env = (const float*)d_in[2];
  const float* areas = (const float*)d_in[3];
  const float* bird = (const float*)d_in[4];
  const float* W_in = (const float*)d_in[5];
  const float* W_ih = (const float*)d_in[6];  // [2,1024,256]
  const float* W_hh = (const float*)d_in[7];  // [2,1024,256]
  const float* b_ih = (const float*)d_in[8];  // [2,1024]
  const float* b_hh = (const float*)d_in[9];  // [2,1024]
  float* out = (float*)d_out;

  const size_t MB = 1 << 20;
  char* w0 = (char*)d_ws;
  // layout: [feats 24MB][PWA 576KB @24MB][PWB 1MB @26MB][bA @28MB][bB @28MB+4K]
  bf16* feats = (bf16*)(w0);
  bf16* PWA = (bf16*)(w0 + 24 * MB);
  bf16* PWB = (bf16*)(w0 + 26 * MB);
  float* bA = (float*)(w0 + 28 * MB);
  float* bB = (float*)(w0 + 28 * MB + 4096);

  feats_kernel<<<(NB * TSTEPS) / 256, 256, 0, stream>>>(x, coords, env, areas, bird, feats);
  packPWA<<<294912 / 256, 256, 0, stream>>>(W_hh, W_ih, W_in, PWA);
  packPWB<<<524288 / 256, 256, 0, stream>>>(W_ih + 1024 * 256, W_hh + 1024 * 256, PWB);
  packBias_kernel<<<2048 / 256, 256, 0, stream>>>(b_ih, b_hh, bA, bB);

  lstm_all<<<256, 512, 0, stream>>>(feats, PWA, PWB, bA, bB, out);
}

// Round 7
// 4310.402 us; speedup vs baseline: 2.0142x; 1.0198x over previous
//
#include <hip/hip_runtime.h>
#include <hip/hip_bf16.h>
#include <cstdint>

#define NB 8192
#define TSTEPS 48

typedef __hip_bfloat16 bf16;
typedef short bf16x8 __attribute__((ext_vector_type(8)));
typedef float f32x4 __attribute__((ext_vector_type(4)));

__device__ __forceinline__ float sigf(float x) { return 1.0f / (1.0f + __expf(-x)); }
__device__ __forceinline__ float tanhf_fast(float x) { return 2.0f / (1.0f + __expf(-2.0f * x)) - 1.0f; }

// async global->LDS, 16B/lane. LDS dest = wave-uniform base + lane*16 (m104).
__device__ __forceinline__ void gld_lds16(const void* g, void* l) {
  typedef const __attribute__((address_space(1))) unsigned int* gp_t;
  typedef __attribute__((address_space(3))) unsigned int* lp_t;
  __builtin_amdgcn_global_load_lds(reinterpret_cast<gp_t>(reinterpret_cast<uintptr_t>(g)),
                                   reinterpret_cast<lp_t>(reinterpret_cast<uintptr_t>(l)),
                                   16, 0, 0);
}

// gate-interleaved packed gate-column order: p = (u>>4)*64 + g*16 + (u&15)
// -> wave w (of 16) owns packed cols [64w, 64w+64) = units [16w,16w+16) x 4 gates;
//    thread's 4 j-frags = gates i,f,g,o of unit u = w*16 + (lane&15).
__device__ __forceinline__ int orig_row_p(int p) {
  int ug = p >> 6, g = (p >> 4) & 3, s = p & 15;
  return g * 256 + ug * 16 + s;  // original row j = g*256 + u
}

// ---------------- feats precompute: [T, N, 32] bf16 (linear chunks; cols 16..31 zero) ----
__global__ void feats_kernel(const float* __restrict__ x, const float* __restrict__ coords,
                             const float* __restrict__ env, const float* __restrict__ areas,
                             const float* __restrict__ bird, bf16* __restrict__ feats) {
  int idx = blockIdx.x * 256 + threadIdx.x;  // = t*NB + n
  int n = idx & (NB - 1);
  int t = idx >> 13;
  __align__(16) bf16 v[32];
  v[0] = __float2bfloat16(x[n * TSTEPS + t]);
  v[1] = __float2bfloat16(coords[n * 2 + 0]);
  v[2] = __float2bfloat16(coords[n * 2 + 1]);
#pragma unroll
  for (int e = 0; e < 10; ++e) v[3 + e] = __float2bfloat16(env[(n * 10 + e) * TSTEPS + t]);
  v[13] = __float2bfloat16(areas[n]);
  v[14] = __float2bfloat16(bird[(n * 2 + 0) * TSTEPS + t]);
  v[15] = __float2bfloat16(bird[(n * 2 + 1) * TSTEPS + t]);
#pragma unroll
  for (int f = 16; f < 32; ++f) v[f] = __float2bfloat16(0.0f);
  bf16* dst = feats + (size_t)idx * 32;
#pragma unroll
  for (int c = 0; c < 4; ++c) ((bf16x8*)dst)[c] = ((const bf16x8*)v)[c];
}

// ---------------- weight packing: per-wave frag-linear order for direct L2->VGPR loads ----
// PWA[w][kb][j][lane][e] (w<16, kb<9, j<4, lane<64, e<8): element = WA[p][k] with
// p = w*64 + j*16 + (lane&15) (gate-interleaved row), k = kb*32 + (lane>>4)*8 + e.
// Per (w,kb,j) = 1KB contiguous -> each wave's 4 frag loads/iter are perfectly coalesced.
__global__ void packPWA(const float* __restrict__ W_hh0, const float* __restrict__ W_ih0,
                        const float* __restrict__ W_in, bf16* __restrict__ PWA) {
  int idx = blockIdx.x * 256 + threadIdx.x;  // < 16*9*4*64*8 = 294912
  int w = idx / 18432, r = idx - w * 18432;  // 18432 = 9*2048
  int kb = r >> 11, rr = r & 2047;
  int j = rr >> 9, lane = (rr >> 3) & 63, e = rr & 7;
  int l16 = lane & 15, quad = lane >> 4;
  int p = w * 64 + j * 16 + l16;
  int jrow = orig_row_p(p);
  int k = kb * 32 + quad * 8 + e;
  float val = 0.0f;
  if (k < 256) {
    val = W_hh0[jrow * 256 + k];
  } else if (k < 272) {
    int f = k - 256;
    float s = 0.0f;
    for (int kk = 0; kk < 256; ++kk) s += W_ih0[jrow * 256 + kk] * W_in[kk * 16 + f];
    val = s;  // Wc0 = W_ih0 @ W_in fused input projection
  }
  PWA[idx] = __float2bfloat16(val);
}

// PWB[w][kb][j][lane][e] (kb<16): k<256 -> W_ih1 (h0 operand), else W_hh1 (h1 operand).
__global__ void packPWB(const float* __restrict__ W_ih1, const float* __restrict__ W_hh1,
                        bf16* __restrict__ PWB) {
  int idx = blockIdx.x * 256 + threadIdx.x;  // < 16*16*4*64*8 = 524288
  int w = idx >> 15, r = idx & 32767;  // 32768 per w
  int kb = r >> 11, rr = r & 2047;
  int j = rr >> 9, lane = (rr >> 3) & 63, e = rr & 7;
  int l16 = lane & 15, quad = lane >> 4;
  int p = w * 64 + j * 16 + l16;
  int jrow = orig_row_p(p);
  int k = kb * 32 + quad * 8 + e;
  float val = (k < 256) ? W_ih1[jrow * 256 + k] : W_hh1[jrow * 256 + (k - 256)];
  PWB[idx] = __float2bfloat16(val);
}

// bias packed [gate][unit] (== original j = g*256+u); sum ih+hh
__global__ void packBias_kernel(const float* __restrict__ b_ih, const float* __restrict__ b_hh,
                                float* __restrict__ bA, float* __restrict__ bB) {
  int idx = blockIdx.x * 256 + threadIdx.x;  // < 2048
  int layer = idx >> 10, r = idx & 1023;
  float v = b_ih[layer * 1024 + r] + b_hh[layer * 1024 + r];
  if (layer == 0) bA[r] = v; else bB[r] = v;
}

// ---------------- R7: R6's zero-communication persistent design, spill-free geometry ----
// R6 failed on register spills (cap 128, demand ~160: WRITE_SIZE 483MB of scratch, which
// thrashed L2 -> 9.2GB HBM fetch). Fix: 16 waves x N=64 per wave -> per-thread state
// acc 32 + bw 32 + c 16 + bias 8 + af 8 + addr ~20 = ~115 < 128. Bonus: 4 waves/SIMD
// (was 2) to hide the L2 weight-load latency; serial cell section halves.
// Block owns 32 rows x all 1024 gate cols; h0/h1 in LDS, c in VGPRs, weights stream
// L2->VGPR (1.6 MB/step/CU, the only recurring traffic -> ~11us/step L2-BW floor).
__global__ __launch_bounds__(1024, 4) void lstm_all(
    const bf16* __restrict__ feats, const bf16* __restrict__ PWA,
    const bf16* __restrict__ PWB, const float* __restrict__ bA,
    const float* __restrict__ bB, float* __restrict__ out) {
  __shared__ __align__(16) bf16 h0s[32 * 264];
  __shared__ __align__(16) bf16 h1s[32 * 264];
  __shared__ __align__(16) bf16 fts[32 * 32];

  const int tid = threadIdx.x;
  const int wid = tid >> 6, lane = tid & 63;
  const int quad = lane >> 4, l16 = lane & 15;
  const int rowbase = blockIdx.x * 32;
  const int u = wid * 16 + l16;

  // zero initial h state (c zeroed in regs)
  for (int i = tid; i < 32 * 264; i += 1024) {
    h0s[i] = __float2bfloat16(0.0f);
    h1s[i] = __float2bfloat16(0.0f);
  }
  // stage feats t=0 (2KB, wave 0)
  if (wid == 0) {
    const bf16* f = feats + (size_t)rowbase * 32 + lane * 8;
    gld_lds16(f, fts);
    gld_lds16(f + 512, fts + 512);
  }
  __syncthreads();  // vmcnt drain -> fts + zeros published

  float bsA[4], bsB[4];
#pragma unroll
  for (int g = 0; g < 4; ++g) {
    bsA[g] = bA[g * 256 + u];
    bsB[g] = bB[g * 256 + u];
  }

  float c0r[8], c1r[8];
#pragma unroll
  for (int i = 0; i < 8; ++i) { c0r[i] = 0.f; c1r[i] = 0.f; }

  const bf16* wA = PWA + (size_t)wid * 18432 + lane * 8;
  const bf16* wB = PWB + (size_t)wid * 32768 + lane * 8;
  float* out_h0 = out;
  float* out_h1 = out + (size_t)NB * 256;
  float* out_c0 = out + (size_t)2 * NB * 256;
  float* out_c1 = out + (size_t)3 * NB * 256;

  f32x4 acc[2][4];
  bf16x8 bw[2][4];

  // register-local cell: thread's 4 j-frags = gates i,f,g,o of unit u
  auto cell = [&](float* cr, bf16* hs, const float* bs, float* oh, float* oc, int last) {
#pragma unroll
    for (int m = 0; m < 2; ++m)
#pragma unroll
      for (int rr = 0; rr < 4; ++rr) {
        const int n = m * 16 + quad * 4 + rr;
        float gi = sigf(acc[m][0][rr] + bs[0]);
        float gf = sigf(acc[m][1][rr] + bs[1]);
        float gg = tanhf_fast(acc[m][2][rr] + bs[2]);
        float go = sigf(acc[m][3][rr] + bs[3]);
        const int ci = m * 4 + rr;
        float cn = gf * cr[ci] + gi * gg;
        float hn = go * tanhf_fast(cn);
        cr[ci] = cn;
        hs[n * 264 + u] = __float2bfloat16(hn);
        if (last) {
          size_t gi2 = (size_t)(rowbase + n) * 256 + u;
          oh[gi2] = hn;
          oc[gi2] = cn;
        }
      }
  };

  for (int t = 0; t < TSTEPS; ++t) {
    const int last = (t == TSTEPS - 1);
    // ---- layer 0: gates = [h0(t-1) | feats_t] @ WA^T (K = 9x32) ----
#pragma unroll
    for (int m = 0; m < 2; ++m)
#pragma unroll
      for (int j = 0; j < 4; ++j) acc[m][j] = f32x4{0.f, 0.f, 0.f, 0.f};
#pragma unroll
    for (int j = 0; j < 4; ++j) bw[0][j] = *(const bf16x8*)(wA + j * 512);
#pragma unroll
    for (int kb = 0; kb < 9; ++kb) {
      if (kb < 8) {
#pragma unroll
        for (int j = 0; j < 4; ++j)
          bw[(kb + 1) & 1][j] = *(const bf16x8*)(wA + (kb + 1) * 2048 + j * 512);
      } else {
#pragma unroll
        for (int j = 0; j < 4; ++j)  // cross-GEMM prefetch: layer-1 kb=0 frags
          bw[1][j] = *(const bf16x8*)(wB + j * 512);
      }
      bf16x8 af[2];
      if (kb < 8) {
#pragma unroll
        for (int m = 0; m < 2; ++m)
          af[m] = *(const bf16x8*)(h0s + (m * 16 + l16) * 264 + kb * 32 + quad * 8);
      } else {
#pragma unroll
        for (int m = 0; m < 2; ++m)
          af[m] = *(const bf16x8*)(fts + (m * 16 + l16) * 32 + quad * 8);
      }
      __builtin_amdgcn_s_setprio(1);
#pragma unroll
      for (int m = 0; m < 2; ++m)
#pragma unroll
        for (int j = 0; j < 4; ++j)
          acc[m][j] = __builtin_amdgcn_mfma_f32_16x16x32_bf16(af[m], bw[kb & 1][j], acc[m][j], 0, 0, 0);
      __builtin_amdgcn_s_setprio(0);
    }
    __syncthreads();  // all waves done reading h0(t-1)/fts
    cell(c0r, h0s, bsA, out_h0, out_c0, last);
    __syncthreads();  // h0(t) published

    // ---- layer 1: gates = [h0(t) | h1(t-1)] @ WB^T (K = 16x32); bw[1] holds kb=0 ----
#pragma unroll
    for (int m = 0; m < 2; ++m)
#pragma unroll
      for (int j = 0; j < 4; ++j) acc[m][j] = f32x4{0.f, 0.f, 0.f, 0.f};
#pragma unroll
    for (int kb = 0; kb < 16; ++kb) {
      if (kb < 15) {
#pragma unroll
        for (int j = 0; j < 4; ++j)
          bw[kb & 1][j] = *(const bf16x8*)(wB + (kb + 1) * 2048 + j * 512);
      }
      bf16x8 af[2];
      if (kb < 8) {
#pragma unroll
        for (int m = 0; m < 2; ++m)
          af[m] = *(const bf16x8*)(h0s + (m * 16 + l16) * 264 + kb * 32 + quad * 8);
      } else {
#pragma unroll
        for (int m = 0; m < 2; ++m)
          af[m] = *(const bf16x8*)(h1s + (m * 16 + l16) * 264 + (kb - 8) * 32 + quad * 8);
      }
      __builtin_amdgcn_s_setprio(1);
#pragma unroll
      for (int m = 0; m < 2; ++m)
#pragma unroll
        for (int j = 0; j < 4; ++j)
          acc[m][j] = __builtin_amdgcn_mfma_f32_16x16x32_bf16(af[m], bw[(kb + 1) & 1][j], acc[m][j], 0, 0, 0);
      __builtin_amdgcn_s_setprio(0);
    }
    // stage feats t+1 (drained by the next barrier's vmcnt(0); read next step)
    if (t < TSTEPS - 1 && wid == 0) {
      const bf16* f = feats + ((size_t)(t + 1) * NB + rowbase) * 32 + lane * 8;
      gld_lds16(f, fts);
      gld_lds16(f + 512, fts + 512);
    }
    __syncthreads();  // h1(t-1) reads done; fts(t+1) published
    cell(c1r, h1s, bsB, out_h1, out_c1, last);
    __syncthreads();  // h1(t) published for next step
  }
}

extern "C" void kernel_launch(void* const* d_in, const int* in_sizes, int n_in,
                              void* d_out, int out_size, void* d_ws, size_t ws_size,
                              hipStream_t stream) {
  const float* x = (const float*)d_in[0];
  const float* coords = (const float*)d_in[1];
  const float* env = (const float*)d_in[2];
  const float* areas = (const float*)d_in[3];
  const float* bird = (const float*)d_in[4];
  const float* W_in = (const float*)d_in[5];
  const float* W_ih = (const float*)d_in[6];  // [2,1024,256]
  const float* W_hh = (const float*)d_in[7];  // [2,1024,256]
  const float* b_ih = (const float*)d_in[8];  // [2,1024]
  const float* b_hh = (const float*)d_in[9];  // [2,1024]
  float* out = (float*)d_out;

  const size_t MB = 1 << 20;
  char* w0 = (char*)d_ws;
  // layout: [feats 24MB][PWA 576KB @24MB][PWB 1MB @26MB][bA @28MB][bB @28MB+4K]
  bf16* feats = (bf16*)(w0);
  bf16* PWA = (bf16*)(w0 + 24 * MB);
  bf16* PWB = (bf16*)(w0 + 26 * MB);
  float* bA = (float*)(w0 + 28 * MB);
  float* bB = (float*)(w0 + 28 * MB + 4096);

  feats_kernel<<<(NB * TSTEPS) / 256, 256, 0, stream>>>(x, coords, env, areas, bird, feats);
  packPWA<<<294912 / 256, 256, 0, stream>>>(W_hh, W_ih, W_in, PWA);
  packPWB<<<524288 / 256, 256, 0, stream>>>(W_ih + 1024 * 256, W_hh + 1024 * 256, PWB);
  packBias_kernel<<<2048 / 256, 256, 0, stream>>>(b_ih, b_hh, bA, bB);

  lstm_all<<<256, 1024, 0, stream>>>(feats, PWA, PWB, bA, bB, out);
}